// Round 6
// baseline (397.543 us; speedup 1.0000x reference)
//
#include <hip/hip_runtime.h>

typedef __attribute__((ext_vector_type(8))) short bf16x8;
typedef __attribute__((ext_vector_type(4))) short bf16x4;
typedef __attribute__((ext_vector_type(4))) float f32x4;
typedef __attribute__((ext_vector_type(16))) float f32x16;

#define MFMA16(a,b,c) __builtin_amdgcn_mfma_f32_16x16x32_bf16((a),(b),(c),0,0,0)
#define MFMA32(a,b,c) __builtin_amdgcn_mfma_f32_32x32x16_bf16((a),(b),(c),0,0,0)

__device__ __forceinline__ short f2bf(float f) {
  union { float f; unsigned u; } v; v.f = f;
  unsigned r = v.u + 0x7FFFu + ((v.u >> 16) & 1u);   // RNE
  return (short)(r >> 16);
}
__device__ __forceinline__ float bf2f(short s) {
  union { unsigned u; float f; } v; v.u = ((unsigned)(unsigned short)s) << 16;
  return v.f;
}
__device__ __forceinline__ unsigned cvtpk(float lo, float hi) {
  unsigned d;
  asm("v_cvt_pk_bf16_f32 %0, %1, %2" : "=v"(d) : "v"(lo), "v"(hi));
  return d;
}
__device__ __forceinline__ float exp2a(float x) {
  float r;
  asm("v_exp_f32 %0, %1" : "=v"(r) : "v"(x));
  return r;
}
__device__ __forceinline__ void async16(const void* g, void* l) {
  __builtin_amdgcn_global_load_lds(
      (const __attribute__((address_space(1))) unsigned*)g,
      (__attribute__((address_space(3))) unsigned*)l, 16, 0, 0);
}

// Q pre-scale: (1/sqrt(256)) * log2(e)  -> softmax runs in exp2 domain
#define QSCALE 0.09016844005556021f

// ------------- convert Wq/Wk/Wv fp32 -> bf16 [3][256][256] -------------
__global__ void cvt_w_kernel(const float* __restrict__ Wq, const float* __restrict__ Wk,
                             const float* __restrict__ Wv, short* __restrict__ Wb) {
  int v = blockIdx.x * 256 + threadIdx.x;        // 24576 units of 8 elems
  int z = v >> 13, r = v & 8191;
  const float* src = ((z == 0) ? Wq : (z == 1) ? Wk : Wv) + r * 8;
  float4 a = *(const float4*)src;
  float4 b = *(const float4*)(src + 4);
  bf16x8 h;
  h[0]=f2bf(a.x); h[1]=f2bf(a.y); h[2]=f2bf(a.z); h[3]=f2bf(a.w);
  h[4]=f2bf(b.x); h[5]=f2bf(b.y); h[6]=f2bf(b.z); h[7]=f2bf(b.w);
  *(bf16x8*)(Wb + z * 65536 + r * 8) = h;
}

// ------------- convert x fp32 -> bf16 [16384][256] -------------
__global__ void cvt_x_kernel(const float* __restrict__ x, short* __restrict__ xb) {
  int v = blockIdx.x * 256 + threadIdx.x;        // 524288 units of 8 elems
  const float* src = x + (size_t)v * 8;
  float4 a = *(const float4*)src;
  float4 b = *(const float4*)(src + 4);
  bf16x8 h;
  h[0]=f2bf(a.x); h[1]=f2bf(a.y); h[2]=f2bf(a.z); h[3]=f2bf(a.w);
  h[4]=f2bf(b.x); h[5]=f2bf(b.y); h[6]=f2bf(b.z); h[7]=f2bf(b.w);
  *(bf16x8*)(xb + (size_t)v * 8) = h;
}

// ------------- proj: grid 1536 = 256 mtiles x 3 z x 2 e-halves; BM=64 -------------
__global__ __launch_bounds__(256, 4) void proj_kernel(
    const short* __restrict__ xb, const short* __restrict__ Wb,
    const float* __restrict__ bq, const float* __restrict__ bk, const float* __restrict__ bv,
    short* __restrict__ Qb, short* __restrict__ Kb, short* __restrict__ VTb)
{
  __shared__ __attribute__((aligned(16))) char xs[32768]; // x tile [64][256] bf16, swizzled
  const int tid = threadIdx.x;
  const int lane = tid & 63;
  const int w = tid >> 6;
  const int l15 = lane & 15, lg = lane >> 4;
  const int bidx = blockIdx.x;
  const int mtile = bidx / 6;
  const int rem = bidx - mtile * 6;
  const int z = rem >> 1, eh = rem & 1;
  const int m0 = mtile * 64;
  const int batch = m0 >> 12;
  const int s0 = m0 & 4095;
  const int e0 = eh * 128 + w * 32;

  // stage xb[m0..+64][256] -> LDS via global_load_lds; pre-swizzled source, linear dest
  const char* xg = (const char*)(xb) + (size_t)m0 * 512;
  #pragma unroll
  for (int c = 0; c < 8; ++c) {
    int v = c * 256 + tid;          // 2048 16B-units, 32 units/row
    int row = v >> 5, u = v & 31;
    async16(xg + (size_t)row * 512 + ((u ^ (row & 31)) * 16), xs + (size_t)v * 16);
  }

  const short* Wz = Wb + z * 65536;
  bf16x8 wf[2][8];
  #pragma unroll
  for (int fc = 0; fc < 2; ++fc)
    #pragma unroll
    for (int ks = 0; ks < 8; ++ks)
      wf[fc][ks] = *(const bf16x8*)(Wz + (size_t)(e0 + fc*16 + l15) * 256 + ks*32 + lg*8);

  __syncthreads();   // drains vmcnt for the x-stage

  if (z < 2) {
    const float* bias = z ? bk : bq;
    short* Ob = z ? Kb : Qb;
    const float scl = z ? 1.0f : QSCALE;
    float bb[2][4];
    #pragma unroll
    for (int fc = 0; fc < 2; ++fc)
      #pragma unroll
      for (int r = 0; r < 4; ++r) bb[fc][r] = bias[e0 + fc*16 + lg*4 + r];
    #pragma unroll
    for (int ms = 0; ms < 4; ++ms) {
      bf16x8 xa[8];
      #pragma unroll
      for (int ks = 0; ks < 8; ++ks) {
        int row = ms * 16 + l15;
        xa[ks] = *(const bf16x8*)(xs + row * 512 + (((ks*4 + lg) ^ (row & 31)) * 16));
      }
      f32x4 acc[2];
      #pragma unroll
      for (int fc = 0; fc < 2; ++fc) acc[fc] = (f32x4){0.f,0.f,0.f,0.f};
      #pragma unroll
      for (int ks = 0; ks < 8; ++ks)
        #pragma unroll
        for (int fc = 0; fc < 2; ++fc)
          acc[fc] = MFMA16(wf[fc][ks], xa[ks], acc[fc]);   // D[e][m]: lane=m, regs=4 e
      #pragma unroll
      for (int fc = 0; fc < 2; ++fc) {
        bf16x4 pv;
        #pragma unroll
        for (int r = 0; r < 4; ++r) pv[r] = f2bf((acc[fc][r] + bb[fc][r]) * scl);
        *(bf16x4*)(Ob + (size_t)(m0 + ms*16 + l15) * 256 + e0 + fc*16 + lg*4) = pv;
      }
    }
  } else {
    float bvr[2];
    #pragma unroll
    for (int fc = 0; fc < 2; ++fc) bvr[fc] = bv[e0 + fc*16 + l15];
    #pragma unroll
    for (int ms = 0; ms < 4; ++ms) {
      bf16x8 xa[8];
      #pragma unroll
      for (int ks = 0; ks < 8; ++ks) {
        int row = ms * 16 + l15;
        xa[ks] = *(const bf16x8*)(xs + row * 512 + (((ks*4 + lg) ^ (row & 31)) * 16));
      }
      f32x4 acc[2];
      #pragma unroll
      for (int fc = 0; fc < 2; ++fc) acc[fc] = (f32x4){0.f,0.f,0.f,0.f};
      #pragma unroll
      for (int ks = 0; ks < 8; ++ks)
        #pragma unroll
        for (int fc = 0; fc < 2; ++fc)
          acc[fc] = MFMA16(xa[ks], wf[fc][ks], acc[fc]);   // D[s][e]: lane=e, regs=4 s
      #pragma unroll
      for (int fc = 0; fc < 2; ++fc) {
        bf16x4 pv;
        #pragma unroll
        for (int r = 0; r < 4; ++r) pv[r] = f2bf(acc[fc][r] + bvr[fc]);
        *(bf16x4*)(VTb + (size_t)(batch*256 + e0 + fc*16 + l15) * 4096 + s0 + ms*16 + lg*4) = pv;
      }
    }
  }
}

// ------------- flash attention: BM=256 (8 waves x 32q), BN=32, NS=4, grid 256 = 1 block/CU,
// ------------- 4-buffer pipeline, counted vmcnt, QK(t+1) interleaved with PV(t)
__global__ __launch_bounds__(512, 2) void attn_kernel(
    const short* __restrict__ Qb, const short* __restrict__ Kb,
    const short* __restrict__ VTb, short* __restrict__ Op, float* __restrict__ mlg)
{
  // 4 bufs x [K 16KB | V 16KB] = 128KB
  __shared__ __attribute__((aligned(16))) char smem[131072];
  const int tid = threadIdx.x;
  const int lane = tid & 63;
  const int w = tid >> 6;
  const int l31 = lane & 31, hi = lane >> 5;

  const int b = blockIdx.x;
  const int c = b & 15;                  // (batch, ns): one combo per XCD-pair slot
  const int batch = c >> 2, ns = c & 3;
  const int qt = b >> 4;                 // 0..15
  const int q0 = qt * 256;
  const int kvbase = ns * 1024;

  const char* Kg = (const char*)(Kb  + (size_t)batch * 4096 * 256);
  const char* Vg = (const char*)(VTb + (size_t)batch * 256 * 4096);

  bf16x8 qf[16];
  {
    const short* qrow = Qb + (size_t)(batch*4096 + q0 + w*32 + l31) * 256;
    #pragma unroll
    for (int ks = 0; ks < 16; ++ks) qf[ks] = *(const bf16x8*)(qrow + ks*16 + hi*8);
  }

  f32x16 o[8];
  #pragma unroll
  for (int i = 0; i < 8; ++i)
    #pragma unroll
    for (int r = 0; r < 16; ++r) o[i][r] = 0.f;
  float m_run = -1e30f, l_run = 0.f;

  auto stage = [&](int buf, int kv0) {
    char* kl = smem + buf * 32768;
    #pragma unroll
    for (int cc = 0; cc < 2; ++cc) {
      int v = cc * 512 + tid;           // 1024 units: 32 rows x 32 units
      int row = v >> 5, s = v & 31;
      async16(Kg + (size_t)(kv0 + row) * 512 + ((s ^ row) * 16), kl + (size_t)v * 16);
    }
    char* vl = smem + buf * 32768 + 16384;
    #pragma unroll
    for (int cc = 0; cc < 2; ++cc) {
      int v = cc * 512 + tid;           // 1024 units: 32 super-rows (8 d) x 32 units
      int sr = v >> 5, j = v & 31;
      int jun = j ^ sr;
      int d = sr * 8 + (jun >> 2), u = jun & 3;
      async16(Vg + (size_t)d * 8192 + (size_t)kv0 * 2 + u * 16, vl + (size_t)v * 16);
    }
  };

  auto QK = [&](int tt, f32x16& st) {
    const char* kl = smem + (tt & 3) * 32768;
    #pragma unroll
    for (int r = 0; r < 16; ++r) st[r] = 0.f;
    #pragma unroll
    for (int ks = 0; ks < 16; ++ks) {
      bf16x8 kf = *(const bf16x8*)(kl + l31 * 512 + (((ks*2 + hi) ^ l31) * 16));
      st = MFMA32(kf, qf[ks], st);
    }
  };

  auto PV = [&](int tt, const bf16x8* pa) {
    const char* vl = smem + (tt & 3) * 32768 + 16384;
    #pragma unroll
    for (int kvf = 0; kvf < 2; ++kvf) {
      #pragma unroll
      for (int df = 0; df < 8; ++df) {
        int sr = df * 4 + (l31 >> 3);
        int j = ((l31 & 7) * 4 + kvf * 2 + hi) ^ sr;
        bf16x8 vb = *(const bf16x8*)(vl + sr * 512 + j * 16);
        o[df] = MFMA32(vb, pa[kvf], o[df]);
      }
    }
  };

  auto SM = [&](f32x16& st, bf16x8* pa) {
    float mx = st[0];
    #pragma unroll
    for (int r = 1; r < 16; ++r) mx = fmaxf(mx, st[r]);
    mx = fmaxf(mx, __shfl_xor(mx, 32));
    if (mx > m_run + 8.f) {              // THR=8 defer-max: rescale only on big jumps
      float alpha = exp2a(m_run - mx);
      l_run *= alpha;
      #pragma unroll
      for (int df = 0; df < 8; ++df) o[df] = o[df] * alpha;
      m_run = mx;
    }
    float lsum = 0.f;
    #pragma unroll
    for (int r = 0; r < 16; ++r) { st[r] = exp2a(st[r] - m_run); lsum += st[r]; }
    l_run += lsum;
    #pragma unroll
    for (int kvf = 0; kvf < 2; ++kvf) {
      unsigned X  = cvtpk(st[8*kvf+0], st[8*kvf+1]);
      unsigned X2 = cvtpk(st[8*kvf+2], st[8*kvf+3]);
      unsigned Y  = cvtpk(st[8*kvf+4], st[8*kvf+5]);
      unsigned Y2 = cvtpk(st[8*kvf+6], st[8*kvf+7]);
      unsigned Xs  = __shfl_xor((int)X, 32);
      unsigned X2s = __shfl_xor((int)X2, 32);
      unsigned Ys  = __shfl_xor((int)Y, 32);
      unsigned Y2s = __shfl_xor((int)Y2, 32);
      union { unsigned u[4]; bf16x8 v; } fr;
      fr.u[0] = hi ? Ys  : X;
      fr.u[1] = hi ? Y2s : X2;
      fr.u[2] = hi ? Y   : Xs;
      fr.u[3] = hi ? Y2  : X2s;
      pa[kvf] = fr.v;
    }
  };

  stage(0, kvbase);
  stage(1, kvbase + 32);
  stage(2, kvbase + 64);
  asm volatile("s_waitcnt vmcnt(16)" ::: "memory");
  __builtin_amdgcn_sched_barrier(0);
  __builtin_amdgcn_s_barrier();
  __builtin_amdgcn_sched_barrier(0);

  f32x16 stA, stB;
  bf16x8 paA[2], paB[2];
  QK(0, stA);

  for (int t = 0; t < 32; t += 2) {
    // ---- even iteration: tile t (stA), QK-ahead on t+1 ----
    SM(stA, paA);
    if (t + 3 < 32) stage((t + 3) & 3, kvbase + (t + 3) * 32);
    if (t < 30) { asm volatile("s_waitcnt vmcnt(16)" ::: "memory"); }
    else        { asm volatile("s_waitcnt vmcnt(0)"  ::: "memory"); }
    __builtin_amdgcn_sched_barrier(0);
    __builtin_amdgcn_s_barrier();
    __builtin_amdgcn_sched_barrier(0);
    __builtin_amdgcn_s_setprio(1);
    QK(t + 1, stB);            // independent of PV(t): scheduler interleaves
    PV(t, paA);
    __builtin_amdgcn_s_setprio(0);
    __builtin_amdgcn_sched_barrier(0);
    __builtin_amdgcn_s_barrier();
    __builtin_amdgcn_sched_barrier(0);

    // ---- odd iteration: tile t+1 (stB), QK-ahead on t+2 ----
    SM(stB, paB);
    if (t + 4 < 32) stage((t + 4) & 3, kvbase + (t + 4) * 32);
    if (t < 28) { asm volatile("s_waitcnt vmcnt(16)" ::: "memory"); }
    else        { asm volatile("s_waitcnt vmcnt(0)"  ::: "memory"); }
    __builtin_amdgcn_sched_barrier(0);
    __builtin_amdgcn_s_barrier();
    __builtin_amdgcn_sched_barrier(0);
    __builtin_amdgcn_s_setprio(1);
    if (t + 2 < 32) QK(t + 2, stA);
    PV(t + 1, paB);
    __builtin_amdgcn_s_setprio(0);
    __builtin_amdgcn_sched_barrier(0);
    __builtin_amdgcn_s_barrier();
    __builtin_amdgcn_sched_barrier(0);
  }

  // ---- epilogue: per-wave partial ----
  float lt = l_run + __shfl_xor(l_run, 32);
  const int qglob = batch*4096 + q0 + w*32 + l31;
  short* op = Op + ((size_t)ns * 16384 + qglob) * 256;
  #pragma unroll
  for (int df = 0; df < 8; ++df)
    #pragma unroll
    for (int g = 0; g < 4; ++g) {
      bf16x4 pv;
      #pragma unroll
      for (int cc = 0; cc < 4; ++cc) pv[cc] = f2bf(o[df][4*g + cc]);
      *(bf16x4*)(op + df*32 + 8*g + 4*hi) = pv;
    }
  if (!hi) {
    mlg[((size_t)ns*16384 + qglob)*2]     = m_run;   // log2-domain
    mlg[((size_t)ns*16384 + qglob)*2 + 1] = lt;
  }
}

// ------------- combine the four kv-split partials (bf16 in, fp32 out; exp2 domain) -------------
__global__ void combine_kernel(const short* __restrict__ Op, const float* __restrict__ mlg,
                               float* __restrict__ out) {
  int idx = blockIdx.x * 256 + threadIdx.x;     // 524288 = 16384 rows x 32 chunks
  int row = idx >> 5, c = idx & 31;
  float m[4], l[4];
  #pragma unroll
  for (int p = 0; p < 4; ++p) {
    m[p] = mlg[((size_t)p*16384 + row)*2];
    l[p] = mlg[((size_t)p*16384 + row)*2 + 1];
  }
  float ms = fmaxf(fmaxf(m[0], m[1]), fmaxf(m[2], m[3]));
  float a[4], den = 0.f;
  #pragma unroll
  for (int p = 0; p < 4; ++p) { a[p] = exp2a(m[p] - ms); den += a[p]*l[p]; }
  float inv = 1.0f / den;
  float acc[8];
  #pragma unroll
  for (int j = 0; j < 8; ++j) acc[j] = 0.f;
  #pragma unroll
  for (int p = 0; p < 4; ++p) {
    bf16x8 v = *(const bf16x8*)(Op + ((size_t)p*16384 + row)*256 + c*8);
    #pragma unroll
    for (int j = 0; j < 8; ++j) acc[j] += a[p] * bf2f(v[j]);
  }
  float4 r0 = {acc[0]*inv, acc[1]*inv, acc[2]*inv, acc[3]*inv};
  float4 r1 = {acc[4]*inv, acc[5]*inv, acc[6]*inv, acc[7]*inv};
  float* po = out + (size_t)row * 256 + c * 8;
  *(float4*)po = r0;
  *(float4*)(po + 4) = r1;
}

extern "C" void kernel_launch(void* const* d_in, const int* in_sizes, int n_in,
                              void* d_out, int out_size, void* d_ws, size_t ws_size,
                              hipStream_t stream) {
  const float* x  = (const float*)d_in[0];
  const float* Wq = (const float*)d_in[1];
  const float* bq = (const float*)d_in[2];
  const float* Wk = (const float*)d_in[3];
  const float* bk = (const float*)d_in[4];
  const float* Wv = (const float*)d_in[5];
  const float* bv = (const float*)d_in[6];
  float* out = (float*)d_out;

  char* ws = (char*)d_ws;
  short* Qb  = (short*)(ws);                         // 8 MiB  [16384][256] bf16 (QSCALE folded)
  short* Kb  = (short*)(ws + 8388608);               // 8 MiB  [16384][256] bf16
  short* VTb = (short*)(ws + 16777216);              // 8 MiB  [4][256][4096] bf16
  short* Wb  = (short*)(ws + 25165824);              // 384 KiB [3][256][256] bf16
  float* mlg = (float*)(ws + 25559040);              // 512 KiB [4][16384][2] f32
  short* Op  = (short*)(ws + 26083328);              // 32 MiB [4][16384][256] bf16
  short* xb  = (short*)(ws + 26083328);              // 8 MiB, ALIASES Op (xb dead before attn)

  cvt_w_kernel<<<dim3(96), dim3(256), 0, stream>>>(Wq, Wk, Wv, Wb);
  cvt_x_kernel<<<dim3(2048), dim3(256), 0, stream>>>(x, xb);
  proj_kernel<<<dim3(1536), dim3(256), 0, stream>>>(xb, Wb, bq, bk, bv, Qb, Kb, VTb);
  attn_kernel<<<dim3(256), dim3(512), 0, stream>>>(Qb, Kb, VTb, Op, mlg);
  combine_kernel<<<dim3(2048), dim3(256), 0, stream>>>(Op, mlg, out);
}

// Round 8
// 335.981 us; speedup vs baseline: 1.1832x; 1.1832x over previous
//
#include <hip/hip_runtime.h>

typedef __attribute__((ext_vector_type(8))) short bf16x8;
typedef __attribute__((ext_vector_type(4))) short bf16x4;
typedef __attribute__((ext_vector_type(4))) float f32x4;
typedef __attribute__((ext_vector_type(16))) float f32x16;

#define MFMA16(a,b,c) __builtin_amdgcn_mfma_f32_16x16x32_bf16((a),(b),(c),0,0,0)
#define MFMA32(a,b,c) __builtin_amdgcn_mfma_f32_32x32x16_bf16((a),(b),(c),0,0,0)

__device__ __forceinline__ short f2bf(float f) {
  union { float f; unsigned u; } v; v.f = f;
  unsigned r = v.u + 0x7FFFu + ((v.u >> 16) & 1u);   // RNE
  return (short)(r >> 16);
}
__device__ __forceinline__ float bf2f(short s) {
  union { unsigned u; float f; } v; v.u = ((unsigned)(unsigned short)s) << 16;
  return v.f;
}
__device__ __forceinline__ unsigned cvtpk(float lo, float hi) {
  unsigned d;
  asm("v_cvt_pk_bf16_f32 %0, %1, %2" : "=v"(d) : "v"(lo), "v"(hi));
  return d;
}
__device__ __forceinline__ float exp2a(float x) {
  float r;
  asm("v_exp_f32 %0, %1" : "=v"(r) : "v"(x));
  return r;
}
__device__ __forceinline__ void async16(const void* g, void* l) {
  __builtin_amdgcn_global_load_lds(
      (const __attribute__((address_space(1))) unsigned*)g,
      (__attribute__((address_space(3))) unsigned*)l, 16, 0, 0);
}

// Q pre-scale: (1/sqrt(256)) * log2(e) -> softmax in exp2 domain
#define QSCALE 0.09016844005556021f

// ------------- fused convert: blocks 0..95 = W (fp32->bf16), 96.. = x -------------
__global__ void cvt_kernel(const float* __restrict__ x,
                           const float* __restrict__ Wq, const float* __restrict__ Wk,
                           const float* __restrict__ Wv,
                           short* __restrict__ Wb, short* __restrict__ xb) {
  int bid = blockIdx.x;
  if (bid < 96) {
    int v = bid * 256 + threadIdx.x;        // 24576 units of 8 elems
    int z = v >> 13, r = v & 8191;
    const float* src = ((z == 0) ? Wq : (z == 1) ? Wk : Wv) + r * 8;
    float4 a = *(const float4*)src;
    float4 b = *(const float4*)(src + 4);
    bf16x8 h;
    h[0]=f2bf(a.x); h[1]=f2bf(a.y); h[2]=f2bf(a.z); h[3]=f2bf(a.w);
    h[4]=f2bf(b.x); h[5]=f2bf(b.y); h[6]=f2bf(b.z); h[7]=f2bf(b.w);
    *(bf16x8*)(Wb + z * 65536 + r * 8) = h;
  } else {
    int v = (bid - 96) * 256 + threadIdx.x; // 524288 units of 8 elems
    const float* src = x + (size_t)v * 8;
    float4 a = *(const float4*)src;
    float4 b = *(const float4*)(src + 4);
    bf16x8 h;
    h[0]=f2bf(a.x); h[1]=f2bf(a.y); h[2]=f2bf(a.z); h[3]=f2bf(a.w);
    h[4]=f2bf(b.x); h[5]=f2bf(b.y); h[6]=f2bf(b.z); h[7]=f2bf(b.w);
    *(bf16x8*)(xb + (size_t)v * 8) = h;
  }
}

// ------------- proj: grid 256 (1/CU), 512 thr; x staged ONCE; wave owns 96 e-cols -------------
__global__ __launch_bounds__(512, 2) void proj_kernel(
    const short* __restrict__ xb, const short* __restrict__ Wb,
    const float* __restrict__ bq, const float* __restrict__ bk, const float* __restrict__ bv,
    short* __restrict__ Qb, short* __restrict__ Kb, short* __restrict__ VTb)
{
  __shared__ __attribute__((aligned(16))) char xs[32768]; // x tile [64][256] bf16, swizzled
  const int tid = threadIdx.x;
  const int lane = tid & 63;
  const int w = tid >> 6;
  const int l15 = lane & 15, lg = lane >> 4;
  const int m0 = blockIdx.x * 64;
  const int batch = m0 >> 12;
  const int s0 = m0 & 4095;

  const char* xg = (const char*)xb + (size_t)m0 * 512;
  #pragma unroll
  for (int cc = 0; cc < 4; ++cc) {
    int v = cc * 512 + tid;          // 2048 16B-units, 32/row
    int row = v >> 5, u = v & 31;
    async16(xg + (size_t)row * 512 + ((u ^ (row & 31)) * 16), xs + (size_t)v * 16);
  }
  __syncthreads();   // drains vmcnt (single stage)

  const int eb = w * 96;
  #pragma unroll
  for (int msh = 0; msh < 2; ++msh) {
    bf16x8 xa[2][8];
    #pragma unroll
    for (int ms2 = 0; ms2 < 2; ++ms2)
      #pragma unroll
      for (int ks = 0; ks < 8; ++ks) {
        int row = msh * 32 + ms2 * 16 + l15;
        xa[ms2][ks] = *(const bf16x8*)(xs + row * 512 + (((ks*4 + lg) ^ (row & 31)) * 16));
      }
    #pragma unroll
    for (int eblk = 0; eblk < 6; ++eblk) {
      int e = eb + eblk * 16;
      int z = e >> 8, ez = e & 255;
      const short* Wz = Wb + z * 65536;
      bf16x8 wf[8];
      #pragma unroll
      for (int ks = 0; ks < 8; ++ks)
        wf[ks] = *(const bf16x8*)(Wz + (size_t)(ez + l15) * 256 + ks*32 + lg*8);
      f32x4 acc[2];
      acc[0] = (f32x4){0.f,0.f,0.f,0.f};
      acc[1] = (f32x4){0.f,0.f,0.f,0.f};
      if (z < 2) {
        #pragma unroll
        for (int ks = 0; ks < 8; ++ks) {
          acc[0] = MFMA16(wf[ks], xa[0][ks], acc[0]);   // lane=m, regs=e
          acc[1] = MFMA16(wf[ks], xa[1][ks], acc[1]);
        }
        const float* bias = z ? bk : bq;
        const float scl = z ? 1.0f : QSCALE;
        short* Ob = z ? Kb : Qb;
        float bb[4];
        #pragma unroll
        for (int r = 0; r < 4; ++r) bb[r] = bias[ez + lg*4 + r];
        #pragma unroll
        for (int ms2 = 0; ms2 < 2; ++ms2) {
          bf16x4 pv;
          #pragma unroll
          for (int r = 0; r < 4; ++r) pv[r] = f2bf((acc[ms2][r] + bb[r]) * scl);
          *(bf16x4*)(Ob + (size_t)(m0 + msh*32 + ms2*16 + l15) * 256 + ez + lg*4) = pv;
        }
      } else {
        #pragma unroll
        for (int ks = 0; ks < 8; ++ks) {
          acc[0] = MFMA16(xa[0][ks], wf[ks], acc[0]);   // lane=e, regs=s
          acc[1] = MFMA16(xa[1][ks], wf[ks], acc[1]);
        }
        float bvv = bv[ez + l15];
        #pragma unroll
        for (int ms2 = 0; ms2 < 2; ++ms2) {
          bf16x4 pv;
          #pragma unroll
          for (int r = 0; r < 4; ++r) pv[r] = f2bf(acc[ms2][r] + bvv);
          *(bf16x4*)(VTb + (size_t)(batch*256 + ez + l15) * 4096 + s0 + msh*32 + ms2*16 + lg*4) = pv;
        }
      }
    }
  }
}

// ------------- flash attention: BM=128 (4qs x 2kvh), BN=64, NS=2, grid 256 (1/CU),
// ------------- K x2 + V x3 buffers (160KB), counted vmcnt(4), kvh ANTI-PHASE classes
__global__ __launch_bounds__(512, 2) void attn_kernel(
    const short* __restrict__ Qb, const short* __restrict__ Kb,
    const short* __restrict__ VTb, short* __restrict__ Op, float* __restrict__ mlg)
{
  // [K0 32K][K1 32K][V0 32K][V1 32K][V2 32K] = 160KB
  __shared__ __attribute__((aligned(16))) char smem[163840];
  const int tid = threadIdx.x;
  const int lane = tid & 63;
  const int w = tid >> 6;
  const int l31 = lane & 31, hi = lane >> 5;
  const int qs = w & 3, kvh = w >> 2;     // kvh doubles as anti-phase class; SIMD k hosts waves k,k+4

  const int b = blockIdx.x;
  const int c = b & 7;                    // one (batch,ns) combo per XCD
  const int batch = c >> 1, ns = c & 1;
  const int qt = b >> 3;                  // 0..31
  const int q0 = qt * 128;
  const int kvbase = ns * 2048;

  const char* Kg = (const char*)(Kb  + (size_t)batch * 4096 * 256);
  const char* Vg = (const char*)(VTb + (size_t)batch * 256 * 4096);

  bf16x8 qf[16];
  {
    const short* qrow = Qb + (size_t)(batch*4096 + q0 + qs*32 + l31) * 256;
    #pragma unroll
    for (int ks = 0; ks < 16; ++ks) qf[ks] = *(const bf16x8*)(qrow + ks*16 + hi*8);
  }

  f32x16 o[8];
  #pragma unroll
  for (int i = 0; i < 8; ++i)
    #pragma unroll
    for (int r = 0; r < 16; ++r) o[i][r] = 0.f;
  float m_run = -1e30f, l_run = 0.f;
  f32x16 st;
  bf16x8 pa[2];

  auto stageK = [&](int kbuf, int kv0) {
    char* kl = smem + kbuf * 32768;
    #pragma unroll
    for (int cc = 0; cc < 4; ++cc) {
      int v = cc * 512 + tid;            // 2048 units: 64 rows x 32
      int row = v >> 5, s = v & 31;
      async16(Kg + (size_t)(kv0 + row) * 512 + ((s ^ (row & 31)) * 16),
              kl + (size_t)v * 16);
    }
  };
  auto stageV = [&](int vbuf, int kv0) {
    char* vl = smem + 65536 + vbuf * 32768;
    #pragma unroll
    for (int cc = 0; cc < 4; ++cc) {
      int v = cc * 512 + tid;            // 2048 units: 64 super-rows (4 d) x 32
      int sr = v >> 5, j = v & 31;
      int jj = j ^ (sr & 31);
      int d = sr * 4 + (jj >> 3), u = jj & 7;
      async16(Vg + (size_t)d * 8192 + (size_t)kv0 * 2 + u * 16,
              vl + (size_t)v * 16);
    }
  };
  auto QK = [&](int t) {
    const char* kl = smem + (t & 1) * 32768;
    #pragma unroll
    for (int r = 0; r < 16; ++r) st[r] = 0.f;
    __builtin_amdgcn_s_setprio(1);
    #pragma unroll
    for (int ks = 0; ks < 16; ++ks) {
      bf16x8 kf = *(const bf16x8*)(kl + (kvh*32 + l31) * 512 + (((ks*2 + hi) ^ l31) * 16));
      st = MFMA32(kf, qf[ks], st);
    }
    __builtin_amdgcn_s_setprio(0);
  };
  auto PV = [&](int t) {
    const char* vl = smem + 65536 + (t % 3) * 32768;
    __builtin_amdgcn_s_setprio(1);
    #pragma unroll
    for (int kvf = 0; kvf < 2; ++kvf) {
      #pragma unroll
      for (int df = 0; df < 8; ++df) {
        int sr = df * 8 + (l31 >> 2);
        int u = kvh * 4 + kvf * 2 + hi;
        int j = (((l31 & 3) << 3) | u) ^ (sr & 31);
        bf16x8 vb = *(const bf16x8*)(vl + sr * 512 + j * 16);
        o[df] = MFMA32(vb, pa[kvf], o[df]);
      }
    }
    __builtin_amdgcn_s_setprio(0);
  };
  auto SM = [&]() {
    float mx = st[0];
    #pragma unroll
    for (int r = 1; r < 16; ++r) mx = fmaxf(mx, st[r]);
    mx = fmaxf(mx, __shfl_xor(mx, 32));
    if (mx > m_run + 8.f) {              // THR=8 defer-max (exp2 domain)
      float alpha = exp2a(m_run - mx);
      l_run *= alpha;
      #pragma unroll
      for (int df = 0; df < 8; ++df) o[df] = o[df] * alpha;
      m_run = mx;
    }
    float lsum = 0.f;
    #pragma unroll
    for (int r = 0; r < 16; ++r) { st[r] = exp2a(st[r] - m_run); lsum += st[r]; }
    l_run += lsum;
    #pragma unroll
    for (int kvf = 0; kvf < 2; ++kvf) {
      unsigned X  = cvtpk(st[8*kvf+0], st[8*kvf+1]);
      unsigned X2 = cvtpk(st[8*kvf+2], st[8*kvf+3]);
      unsigned Y  = cvtpk(st[8*kvf+4], st[8*kvf+5]);
      unsigned Y2 = cvtpk(st[8*kvf+6], st[8*kvf+7]);
      unsigned Xs  = __shfl_xor((int)X, 32);
      unsigned X2s = __shfl_xor((int)X2, 32);
      unsigned Ys  = __shfl_xor((int)Y, 32);
      unsigned Y2s = __shfl_xor((int)Y2, 32);
      union { unsigned u[4]; bf16x8 v; } fr;
      fr.u[0] = hi ? Ys  : X;
      fr.u[1] = hi ? Y2s : X2;
      fr.u[2] = hi ? Y   : Xs;
      fr.u[3] = hi ? Y2  : X2s;
      pa[kvf] = fr.v;
    }
  };

  // prologue: K(0), V(0), V(1)
  stageK(0, kvbase);
  stageV(0, kvbase);
  stageV(1, kvbase + 64);

  for (int t = 0; t < 32; ++t) {
    if (t < 31) { asm volatile("s_waitcnt vmcnt(4)" ::: "memory"); }
    else        { asm volatile("s_waitcnt vmcnt(0)" ::: "memory"); }
    __builtin_amdgcn_sched_barrier(0);
    __builtin_amdgcn_s_barrier();            // A: K(t), V(t) landed; everyone done with t-1
    __builtin_amdgcn_sched_barrier(0);
    if (t + 1 < 32) stageK((t + 1) & 1, kvbase + (t + 1) * 64);

    if (kvh == 0) {
      QK(t);
      SM();
    } else {
      if (t > 0) PV(t - 1);                  // pa from previous region's SM
      QK(t);
    }

    __builtin_amdgcn_sched_barrier(0);
    __builtin_amdgcn_s_barrier();            // B: all V(t-1) reads done
    __builtin_amdgcn_sched_barrier(0);
    if (t + 2 < 32) stageV((t + 2) % 3, kvbase + (t + 2) * 64);

    if (kvh == 0) PV(t);
    else SM();
  }
  if (kvh == 1) PV(31);

  // ---- epilogue: per-wave partial p = kvh*2 + ns ----
  float lt = l_run + __shfl_xor(l_run, 32);
  const int p = kvh * 2 + ns;
  const int qglob = batch*4096 + q0 + qs*32 + l31;
  short* op = Op + ((size_t)p * 16384 + qglob) * 256;
  #pragma unroll
  for (int df = 0; df < 8; ++df)
    #pragma unroll
    for (int g = 0; g < 4; ++g) {
      bf16x4 pv;
      #pragma unroll
      for (int cc2 = 0; cc2 < 4; ++cc2) pv[cc2] = f2bf(o[df][4*g + cc2]);
      *(bf16x4*)(op + df*32 + 8*g + 4*hi) = pv;
    }
  if (!hi) {
    mlg[((size_t)p*16384 + qglob)*2]     = m_run;   // log2-domain
    mlg[((size_t)p*16384 + qglob)*2 + 1] = lt;
  }
}

// ------------- combine the four partials (bf16 in, fp32 out; exp2 domain) -------------
__global__ void combine_kernel(const short* __restrict__ Op, const float* __restrict__ mlg,
                               float* __restrict__ out) {
  int idx = blockIdx.x * 256 + threadIdx.x;     // 524288 = 16384 rows x 32 chunks
  int row = idx >> 5, c = idx & 31;
  float m[4], l[4];
  #pragma unroll
  for (int p = 0; p < 4; ++p) {
    m[p] = mlg[((size_t)p*16384 + row)*2];
    l[p] = mlg[((size_t)p*16384 + row)*2 + 1];
  }
  float ms = fmaxf(fmaxf(m[0], m[1]), fmaxf(m[2], m[3]));
  float a[4], den = 0.f;
  #pragma unroll
  for (int p = 0; p < 4; ++p) { a[p] = exp2a(m[p] - ms); den += a[p]*l[p]; }
  float inv = 1.0f / den;
  float acc[8];
  #pragma unroll
  for (int j = 0; j < 8; ++j) acc[j] = 0.f;
  #pragma unroll
  for (int p = 0; p < 4; ++p) {
    bf16x8 v = *(const bf16x8*)(Op + ((size_t)p*16384 + row)*256 + c*8);
    #pragma unroll
    for (int j = 0; j < 8; ++j) acc[j] += a[p] * bf2f(v[j]);
  }
  float4 r0 = {acc[0]*inv, acc[1]*inv, acc[2]*inv, acc[3]*inv};
  float4 r1 = {acc[4]*inv, acc[5]*inv, acc[6]*inv, acc[7]*inv};
  float* po = out + (size_t)row * 256 + c * 8;
  *(float4*)po = r0;
  *(float4*)(po + 4) = r1;
}

extern "C" void kernel_launch(void* const* d_in, const int* in_sizes, int n_in,
                              void* d_out, int out_size, void* d_ws, size_t ws_size,
                              hipStream_t stream) {
  const float* x  = (const float*)d_in[0];
  const float* Wq = (const float*)d_in[1];
  const float* bq = (const float*)d_in[2];
  const float* Wk = (const float*)d_in[3];
  const float* bk = (const float*)d_in[4];
  const float* Wv = (const float*)d_in[5];
  const float* bv = (const float*)d_in[6];
  float* out = (float*)d_out;

  char* ws = (char*)d_ws;
  short* Qb  = (short*)(ws);                         // 8 MiB  [16384][256] bf16 (QSCALE folded)
  short* Kb  = (short*)(ws + 8388608);               // 8 MiB  [16384][256] bf16
  short* VTb = (short*)(ws + 16777216);              // 8 MiB  [4][256][4096] bf16
  short* Wb  = (short*)(ws + 25165824);              // 384 KiB [3][256][256] bf16
  float* mlg = (float*)(ws + 25559040);              // 512 KiB [4][16384][2] f32
  short* Op  = (short*)(ws + 26083328);              // 32 MiB [4][16384][256] bf16
  short* xb  = (short*)(ws + 26083328);              // 8 MiB, ALIASES Op (xb dead before attn)

  cvt_kernel<<<dim3(2144), dim3(256), 0, stream>>>(x, Wq, Wk, Wv, Wb, xb);
  proj_kernel<<<dim3(256), dim3(512), 0, stream>>>(xb, Wb, bq, bk, bv, Qb, Kb, VTb);
  attn_kernel<<<dim3(256), dim3(512), 0, stream>>>(Qb, Kb, VTb, Op, mlg);
  combine_kernel<<<dim3(2048), dim3(256), 0, stream>>>(Op, mlg, out);
}